// Round 1
// baseline (596.011 us; speedup 1.0000x reference)
//
#include <hip/hip_runtime.h>
#include <math.h>

#define EPSV 1e-6f
#define NTOK 8192
#define NE   16384
#define DIM  256

using short8 = __attribute__((ext_vector_type(8))) short;
using f32x4v = __attribute__((ext_vector_type(4))) float;

__device__ __forceinline__ unsigned short f2bf(float v) {
    unsigned int u = __float_as_uint(v);
    u += 0x7fffu + ((u >> 16) & 1u);   // RNE
    return (unsigned short)(u >> 16);
}
__device__ __forceinline__ float bf2f(unsigned short h) {
    return __uint_as_float(((unsigned int)h) << 16);
}

__device__ __forceinline__ void gload_lds16(const void* g, void* s) {
    __builtin_amdgcn_global_load_lds(
        (const __attribute__((address_space(1))) void*)g,
        (__attribute__((address_space(3))) void*)s, 16, 0, 0);
}

// ---------------------------------------------------------------- K0a:
// z (b,c,h,w) -> z_flat (tok, c) fp32 + bf16 hi/lo split. Also zeroes loss acc.
__global__ __launch_bounds__(256) void k0a_transpose(
    const float* __restrict__ zin, float* __restrict__ z_flat,
    unsigned short* __restrict__ zh, unsigned short* __restrict__ zl,
    float* __restrict__ loss_ws) {
    __shared__ float tile[64][65];
    const int tid = threadIdx.x;
    if (blockIdx.x == 0 && blockIdx.y == 0 && blockIdx.z == 0 && tid == 0)
        loss_ws[0] = 0.0f;
    const int yx0 = blockIdx.x * 64, c0 = blockIdx.y * 64, b = blockIdx.z;
    const int sub = tid >> 6, ln = tid & 63;
#pragma unroll
    for (int j = 0; j < 16; ++j) {
        int cl = j * 4 + sub;
        tile[cl][ln] = zin[((size_t)(b * 256 + c0 + cl) << 10) + yx0 + ln];
    }
    __syncthreads();
#pragma unroll
    for (int j = 0; j < 16; ++j) {
        int tl = j * 4 + sub;
        float v = tile[ln][tl];
        size_t o = (size_t)(b * 1024 + yx0 + tl) * 256 + c0 + ln;
        z_flat[o] = v;
        unsigned short h = f2bf(v);
        zh[o] = h;
        zl[o] = f2bf(v - bf2f(h));
    }
}

// ---------------------------------------------------------------- K0b:
// sz[t] = sum(z^2) per token, fp64 accumulate -> correctly rounded fp32.
__global__ __launch_bounds__(256) void k0b_sz(const float* __restrict__ z_flat,
                                              float* __restrict__ sz) {
    const int w = threadIdx.x >> 6, lane = threadIdx.x & 63;
    const int t = blockIdx.x * 4 + w;
    const float4 v = *(const float4*)(z_flat + (size_t)t * 256 + lane * 4);
    double s = (double)v.x * v.x + (double)v.y * v.y + (double)v.z * v.z +
               (double)v.w * v.w;
#pragma unroll
    for (int m = 1; m < 64; m <<= 1) s += __shfl_xor(s, m);
    if (lane == 0) sz[t] = (float)s;
}

// ---------------------------------------------------------------- K0c:
// emb[n][c] = sum_k codebook[n][k] * W[c][k], fp32, 64x64 tiles, BK=64.
// Also writes bf16 hi/lo split of emb.
__global__ __launch_bounds__(256) void k0c_emb(
    const float* __restrict__ cb, const float* __restrict__ Wm,
    float* __restrict__ emb, unsigned short* __restrict__ eh,
    unsigned short* __restrict__ el) {
    __shared__ float cbS[64][68];
    __shared__ float wS[64][68];
    const int tid = threadIdx.x;
    const int n0 = blockIdx.x * 64, c0 = blockIdx.y * 64;
    const int tx = tid & 15, ty = tid >> 4;
    float acc[4][4] = {};
    for (int kc = 0; kc < 4; ++kc) {
        __syncthreads();
#pragma unroll
        for (int it = 0; it < 16; ++it) {
            int idx = it * 256 + tid;
            int rw = idx >> 6, kk = idx & 63;
            cbS[rw][kk] = cb[(size_t)(n0 + rw) * 256 + kc * 64 + kk];
            wS[rw][kk]  = Wm[(size_t)(c0 + rw) * 256 + kc * 64 + kk];
        }
        __syncthreads();
#pragma unroll
        for (int k4 = 0; k4 < 16; ++k4) {
            float4 ra[4], rb[4];
#pragma unroll
            for (int a = 0; a < 4; ++a)
                ra[a] = *(const float4*)&cbS[ty * 4 + a][k4 * 4];
#pragma unroll
            for (int bb = 0; bb < 4; ++bb)
                rb[bb] = *(const float4*)&wS[tx * 4 + bb][k4 * 4];
#pragma unroll
            for (int a = 0; a < 4; ++a)
#pragma unroll
                for (int bb = 0; bb < 4; ++bb)
                    acc[a][bb] += ra[a].x * rb[bb].x + ra[a].y * rb[bb].y +
                                  ra[a].z * rb[bb].z + ra[a].w * rb[bb].w;
        }
    }
#pragma unroll
    for (int a = 0; a < 4; ++a) {
        int n = n0 + ty * 4 + a;
#pragma unroll
        for (int bb = 0; bb < 4; ++bb) {
            int c = c0 + tx * 4 + bb;
            size_t o = (size_t)n * 256 + c;
            float v = acc[a][bb];
            emb[o] = v;
            unsigned short h = f2bf(v);
            eh[o] = h;
            el[o] = f2bf(v - bf2f(h));
        }
    }
}

// ---------------------------------------------------------------- K0d:
// se[n] = sum(emb^2) per code row, fp64 accumulate.
__global__ __launch_bounds__(256) void k0d_se(const float* __restrict__ emb,
                                              float* __restrict__ se) {
    const int w = threadIdx.x >> 6, lane = threadIdx.x & 63;
    const int n = blockIdx.x * 4 + w;
    const float4 v = *(const float4*)(emb + (size_t)n * 256 + lane * 4);
    double s = (double)v.x * v.x + (double)v.y * v.y + (double)v.z * v.z +
               (double)v.w * v.w;
#pragma unroll
    for (int m = 1; m < 64; m <<= 1) s += __shfl_xor(s, m);
    if (lane == 0) se[n] = (float)s;
}

// ---------------------------------------------------------------- K1:
// Fused bf16x2 (3-term) MFMA GEMM + argmin.
// Grid (M/128, NE/2048). Block: 256 thr = 4 waves in 2x2 (64x64 each).
// LDS 64KB: 4 tiles [Ah|Al|Bh|Bl], each 1024 16B-units laid [kg][row]
// (k-outer) so global_load_lds staging is lane-contiguous and ds_read_b128
// is conflict-free (2-way max = free).
__global__ __launch_bounds__(256, 2) void k1_dist_argmin(
    const unsigned short* __restrict__ zh, const unsigned short* __restrict__ zl,
    const unsigned short* __restrict__ eh, const unsigned short* __restrict__ el,
    const float* __restrict__ sz, const float* __restrict__ se,
    float* __restrict__ pval, int* __restrict__ pidx) {
    __shared__ short8 smemFr[4096];  // 65536 B
    const int tid = threadIdx.x;
    const int w = tid >> 6;
    const int lane = tid & 63;
    const int quad = lane >> 4, lr = lane & 15;
    const int wr = w & 1, wc = w >> 1;
    const int tokBase = blockIdx.x * 128;
    const int slab = blockIdx.y;
    const int slabBase = slab * 2048;

    float szr[4][4];
#pragma unroll
    for (int mt = 0; mt < 4; ++mt)
#pragma unroll
        for (int rr = 0; rr < 4; ++rr)
            szr[mt][rr] = sz[tokBase + wr * 64 + mt * 16 + quad * 4 + rr];

    float minv[4][4];
    int mini[4][4];
#pragma unroll
    for (int mt = 0; mt < 4; ++mt)
#pragma unroll
        for (int rr = 0; rr < 4; ++rr) {
            minv[mt][rr] = INFINITY;
            mini[mt][rr] = 0;
        }

    for (int nch = 0; nch < 16; ++nch) {
        const int colBase = slabBase + nch * 128;
        f32x4v acc[4][4];
#pragma unroll
        for (int mt = 0; mt < 4; ++mt)
#pragma unroll
            for (int nt = 0; nt < 4; ++nt)
                acc[mt][nt] = (f32x4v){0.f, 0.f, 0.f, 0.f};

        for (int kc = 0; kc < 4; ++kc) {
            __syncthreads();  // previous chunk's reads done
            const int kbase = kc * 64;
#pragma unroll
            for (int i = 0; i < 16; ++i) {
                int U = i * 256 + tid;
                int tile = (i * 4 + w) >> 4;  // wave-uniform
                int V = U & 1023;
                int kg = V >> 7, r = V & 127;
                int kcol = kbase + kg * 8;
                const unsigned short* g;
                if (tile == 0)      g = zh + (size_t)(tokBase + r) * 256 + kcol;
                else if (tile == 1) g = zl + (size_t)(tokBase + r) * 256 + kcol;
                else if (tile == 2) g = eh + (size_t)(colBase + r) * 256 + kcol;
                else                g = el + (size_t)(colBase + r) * 256 + kcol;
                gload_lds16(g, (char*)smemFr + ((size_t)(i * 4 + w) << 10));
            }
            __syncthreads();  // staging landed (compiler emits vmcnt(0))
#pragma unroll
            for (int ks = 0; ks < 2; ++ks) {
                const int kgq = ks * 4 + quad;
                short8 Ah[4], Al[4], Bh[4], Bl[4];
#pragma unroll
                for (int mt = 0; mt < 4; ++mt) {
                    int u = kgq * 128 + wr * 64 + mt * 16 + lr;
                    Ah[mt] = smemFr[u];
                    Al[mt] = smemFr[1024 + u];
                }
#pragma unroll
                for (int nt = 0; nt < 4; ++nt) {
                    int u = kgq * 128 + wc * 64 + nt * 16 + lr;
                    Bh[nt] = smemFr[2048 + u];
                    Bl[nt] = smemFr[3072 + u];
                }
#pragma unroll
                for (int mt = 0; mt < 4; ++mt)
#pragma unroll
                    for (int nt = 0; nt < 4; ++nt) {
                        f32x4v a = acc[mt][nt];
                        a = __builtin_amdgcn_mfma_f32_16x16x32_bf16(Ah[mt], Bh[nt], a, 0, 0, 0);
                        a = __builtin_amdgcn_mfma_f32_16x16x32_bf16(Ah[mt], Bl[nt], a, 0, 0, 0);
                        a = __builtin_amdgcn_mfma_f32_16x16x32_bf16(Al[mt], Bh[nt], a, 0, 0, 0);
                        acc[mt][nt] = a;
                    }
            }
        }
        // fold: d = fl(fl(sz+se) - 2*dot), replicate reference rounding
#pragma unroll
        for (int nt = 0; nt < 4; ++nt) {
            const int colg = colBase + wc * 64 + nt * 16 + lr;
            const float sec = se[colg];
#pragma unroll
            for (int mt = 0; mt < 4; ++mt)
#pragma unroll
                for (int rr = 0; rr < 4; ++rr) {
                    float d = __fsub_rn(__fadd_rn(szr[mt][rr], sec),
                                        2.0f * acc[mt][nt][rr]);
                    if (d < minv[mt][rr]) {   // strict <: first index wins
                        minv[mt][rr] = d;
                        mini[mt][rr] = colg;
                    }
                }
        }
    }

    // cross-lane reduce within 16-lane groups (cols), min with min-idx tiebreak
#pragma unroll
    for (int st = 1; st < 16; st <<= 1) {
#pragma unroll
        for (int mt = 0; mt < 4; ++mt)
#pragma unroll
            for (int rr = 0; rr < 4; ++rr) {
                float ov = __shfl_xor(minv[mt][rr], st);
                int oi = __shfl_xor(mini[mt][rr], st);
                if (ov < minv[mt][rr] ||
                    (ov == minv[mt][rr] && oi < mini[mt][rr])) {
                    minv[mt][rr] = ov;
                    mini[mt][rr] = oi;
                }
            }
    }

    __syncthreads();
    float* mv = (float*)smemFr;          // [128][2]
    int* mi = (int*)(mv + 256);
    if (lr == 0) {
#pragma unroll
        for (int mt = 0; mt < 4; ++mt)
#pragma unroll
            for (int rr = 0; rr < 4; ++rr) {
                int rl = wr * 64 + mt * 16 + quad * 4 + rr;
                mv[rl * 2 + wc] = minv[mt][rr];
                mi[rl * 2 + wc] = mini[mt][rr];
            }
    }
    __syncthreads();
    if (tid < 128) {
        float v0 = mv[tid * 2], v1 = mv[tid * 2 + 1];
        int i0 = mi[tid * 2], i1 = mi[tid * 2 + 1];
        bool take1 = (v1 < v0) || (v1 == v0 && i1 < i0);
        pval[(size_t)(tokBase + tid) * 8 + slab] = take1 ? v1 : v0;
        pidx[(size_t)(tokBase + tid) * 8 + slab] = take1 ? i1 : i0;
    }
}

// ---------------------------------------------------------------- K3a:
// per-token: reduce 8 slab partials -> final index; rotation scalars
// alpha/beta; loss partial (atomic); index (as float) to out.
__global__ __launch_bounds__(256) void k3a_token(
    const float* __restrict__ z_flat, const float* __restrict__ emb,
    const float* __restrict__ pval, const int* __restrict__ pidx,
    float* __restrict__ alpha, float* __restrict__ beta,
    int* __restrict__ idxf, float* __restrict__ out,
    float* __restrict__ loss_ws) {
    const int w = threadIdx.x >> 6, lane = threadIdx.x & 63;
    const int t = blockIdx.x * 4 + w;
    int best = 0;
    if (lane == 0) {
        float bv = INFINITY;
        int bi = 0;
#pragma unroll
        for (int s = 0; s < 8; ++s) {
            float v = pval[(size_t)t * 8 + s];
            int ii = pidx[(size_t)t * 8 + s];
            if (v < bv || (v == bv && ii < bi)) { bv = v; bi = ii; }
        }
        best = bi;
    }
    best = __shfl(best, 0);

    const float4 zv = *(const float4*)(z_flat + (size_t)t * 256 + lane * 4);
    const float4 ev = *(const float4*)(emb + (size_t)best * 256 + lane * 4);
    float szs = zv.x * zv.x + zv.y * zv.y + zv.z * zv.z + zv.w * zv.w;
    float ses = ev.x * ev.x + ev.y * ev.y + ev.z * ev.z + ev.w * ev.w;
    float zes = zv.x * ev.x + zv.y * ev.y + zv.z * ev.z + zv.w * ev.w;
    float dx = zv.x - ev.x, dy = zv.y - ev.y, dz = zv.z - ev.z, dw = zv.w - ev.w;
    float sqs = dx * dx + dy * dy + dz * dz + dw * dw;
#pragma unroll
    for (int m = 1; m < 64; m <<= 1) {
        szs += __shfl_xor(szs, m);
        ses += __shfl_xor(ses, m);
        zes += __shfl_xor(zes, m);
        sqs += __shfl_xor(sqs, m);
    }
    if (lane == 0) {
        float ns = sqrtf(szs), nt = sqrtf(ses);
        float inv_s = 1.0f / (ns + EPSV);
        float inv_t = 1.0f / (nt + EPSV);
        float s2 = szs * inv_s;                      // z . u
        float su = szs * inv_s * inv_s;
        float sq = ses * inv_t * inv_t;
        float uq = zes * inv_s * inv_t;
        float nw = sqrtf(su + sq + 2.0f * uq);
        float inv_w = 1.0f / (nw + EPSV);
        float s1 = (s2 + zes * inv_t) * inv_w;       // z . w_
        float scale = nt * inv_s;
        float a = scale * (1.0f - 2.0f * s1 * inv_w * inv_s);
        float bb = scale * inv_t * 2.0f * (s2 - s1 * inv_w);
        alpha[t] = a;
        beta[t] = bb;
        idxf[t] = best;
        out[2097153 + t] = (float)best;
        atomicAdd(loss_ws, sqs);
    }
}

// ---------------------------------------------------------------- K4: loss
__global__ void k4_loss(float* __restrict__ out,
                        const float* __restrict__ loss_ws) {
    out[2097152] = 1.25f * loss_ws[0] * (1.0f / 2097152.0f);
}

// ---------------------------------------------------------------- K3b:
// z_q[b][c][yx] = alpha[t]*z[b][c][yx] + beta[t]*emb[idx[t]][c]
__global__ __launch_bounds__(256) void k3b_zq(
    const float* __restrict__ zin, const float* __restrict__ emb,
    const float* __restrict__ alpha, const float* __restrict__ beta,
    const int* __restrict__ idxf, float* __restrict__ out) {
    const int i = blockIdx.x * 256 + threadIdx.x;
    const int c = (i >> 10) & 255;
    const int t = ((i >> 18) << 10) | (i & 1023);
    out[i] = alpha[t] * zin[i] + beta[t] * emb[(size_t)idxf[t] * 256 + c];
}

// ----------------------------------------------------------------
extern "C" void kernel_launch(void* const* d_in, const int* in_sizes, int n_in,
                              void* d_out, int out_size, void* d_ws,
                              size_t ws_size, hipStream_t stream) {
    (void)in_sizes; (void)n_in; (void)out_size; (void)ws_size;
    const float* zin = (const float*)d_in[0];
    const float* cb  = (const float*)d_in[1];
    const float* Wm  = (const float*)d_in[2];
    float* out = (float*)d_out;
    char* ws = (char*)d_ws;

    float*          z_flat = (float*)(ws + 0);                     //  8 MB
    unsigned short* zh     = (unsigned short*)(ws + 8388608);      //  4 MB
    unsigned short* zl     = (unsigned short*)(ws + 12582912);     //  4 MB
    float*          emb    = (float*)(ws + 16777216);              // 16 MB
    unsigned short* eh     = (unsigned short*)(ws + 33554432);     //  8 MB
    unsigned short* el     = (unsigned short*)(ws + 41943040);     //  8 MB
    float*          sz     = (float*)(ws + 50331648);              // 32 KB
    float*          se     = (float*)(ws + 50364416);              // 64 KB
    float*          pval   = (float*)(ws + 50429952);              // 256 KB
    int*            pidx   = (int*)(ws + 50692096);                // 256 KB
    float*          alpha  = (float*)(ws + 50954240);              // 32 KB
    float*          beta   = (float*)(ws + 50987008);              // 32 KB
    int*            idxf   = (int*)(ws + 51019776);                // 32 KB
    float*          lossw  = (float*)(ws + 51052544);              // 4 B

    k0a_transpose<<<dim3(16, 4, 8), 256, 0, stream>>>(zin, z_flat, zh, zl, lossw);
    k0b_sz<<<2048, 256, 0, stream>>>(z_flat, sz);
    k0c_emb<<<dim3(256, 4), 256, 0, stream>>>(cb, Wm, emb, eh, el);
    k0d_se<<<4096, 256, 0, stream>>>(emb, se);
    k1_dist_argmin<<<dim3(64, 8), 256, 0, stream>>>(zh, zl, eh, el, sz, se,
                                                    pval, pidx);
    k3a_token<<<2048, 256, 0, stream>>>(z_flat, emb, pval, pidx, alpha, beta,
                                        idxf, out, lossw);
    k4_loss<<<1, 1, 0, stream>>>(out, lossw);
    k3b_zq<<<8192, 256, 0, stream>>>(zin, emb, alpha, beta, idxf, out);
}

// Round 2
// 340.229 us; speedup vs baseline: 1.7518x; 1.7518x over previous
//
#include <hip/hip_runtime.h>
#include <math.h>

#define EPSV 1e-6f
#define NTOK 8192
#define NE   16384
#define DIM  256

using short8 = __attribute__((ext_vector_type(8))) short;
using f32x4v = __attribute__((ext_vector_type(4))) float;

__device__ __forceinline__ unsigned short f2bf(float v) {
    unsigned int u = __float_as_uint(v);
    u += 0x7fffu + ((u >> 16) & 1u);   // RNE
    return (unsigned short)(u >> 16);
}
__device__ __forceinline__ float bf2f(unsigned short h) {
    return __uint_as_float(((unsigned int)h) << 16);
}

__device__ __forceinline__ void gload_lds16(const void* g, void* s) {
    __builtin_amdgcn_global_load_lds(
        (const __attribute__((address_space(1))) void*)g,
        (__attribute__((address_space(3))) void*)s, 16, 0, 0);
}

// ---------------------------------------------------------------- K0a:
// z (b,c,h,w) -> z_flat (tok, c) fp32 + bf16 hi/lo split.
__global__ __launch_bounds__(256) void k0a_transpose(
    const float* __restrict__ zin, float* __restrict__ z_flat,
    unsigned short* __restrict__ zh, unsigned short* __restrict__ zl) {
    __shared__ float tile[64][65];
    const int tid = threadIdx.x;
    const int yx0 = blockIdx.x * 64, c0 = blockIdx.y * 64, b = blockIdx.z;
    const int sub = tid >> 6, ln = tid & 63;
#pragma unroll
    for (int j = 0; j < 16; ++j) {
        int cl = j * 4 + sub;
        tile[cl][ln] = zin[((size_t)(b * 256 + c0 + cl) << 10) + yx0 + ln];
    }
    __syncthreads();
#pragma unroll
    for (int j = 0; j < 16; ++j) {
        int tl = j * 4 + sub;
        float v = tile[ln][tl];
        size_t o = (size_t)(b * 1024 + yx0 + tl) * 256 + c0 + ln;
        z_flat[o] = v;
        unsigned short h = f2bf(v);
        zh[o] = h;
        zl[o] = f2bf(v - bf2f(h));
    }
}

// ---------------------------------------------------------------- K0b:
// sz[t] = sum(z^2) per token, fp64 accumulate -> correctly rounded fp32.
__global__ __launch_bounds__(256) void k0b_sz(const float* __restrict__ z_flat,
                                              float* __restrict__ sz) {
    const int w = threadIdx.x >> 6, lane = threadIdx.x & 63;
    const int t = blockIdx.x * 4 + w;
    const float4 v = *(const float4*)(z_flat + (size_t)t * 256 + lane * 4);
    double s = (double)v.x * v.x + (double)v.y * v.y + (double)v.z * v.z +
               (double)v.w * v.w;
#pragma unroll
    for (int m = 1; m < 64; m <<= 1) s += __shfl_xor(s, m);
    if (lane == 0) sz[t] = (float)s;
}

// ---------------------------------------------------------------- K0c:
// emb[n][c] = sum_k codebook[n][k] * W[c][k], fp32, 64x64 tiles, BK=64.
__global__ __launch_bounds__(256) void k0c_emb(
    const float* __restrict__ cb, const float* __restrict__ Wm,
    float* __restrict__ emb, unsigned short* __restrict__ eh,
    unsigned short* __restrict__ el) {
    __shared__ float cbS[64][68];
    __shared__ float wS[64][68];
    const int tid = threadIdx.x;
    const int n0 = blockIdx.x * 64, c0 = blockIdx.y * 64;
    const int tx = tid & 15, ty = tid >> 4;
    float acc[4][4] = {};
    for (int kc = 0; kc < 4; ++kc) {
        __syncthreads();
#pragma unroll
        for (int it = 0; it < 16; ++it) {
            int idx = it * 256 + tid;
            int rw = idx >> 6, kk = idx & 63;
            cbS[rw][kk] = cb[(size_t)(n0 + rw) * 256 + kc * 64 + kk];
            wS[rw][kk]  = Wm[(size_t)(c0 + rw) * 256 + kc * 64 + kk];
        }
        __syncthreads();
#pragma unroll
        for (int k4 = 0; k4 < 16; ++k4) {
            float4 ra[4], rb[4];
#pragma unroll
            for (int a = 0; a < 4; ++a)
                ra[a] = *(const float4*)&cbS[ty * 4 + a][k4 * 4];
#pragma unroll
            for (int bb = 0; bb < 4; ++bb)
                rb[bb] = *(const float4*)&wS[tx * 4 + bb][k4 * 4];
#pragma unroll
            for (int a = 0; a < 4; ++a)
#pragma unroll
                for (int bb = 0; bb < 4; ++bb)
                    acc[a][bb] += ra[a].x * rb[bb].x + ra[a].y * rb[bb].y +
                                  ra[a].z * rb[bb].z + ra[a].w * rb[bb].w;
        }
    }
#pragma unroll
    for (int a = 0; a < 4; ++a) {
        int n = n0 + ty * 4 + a;
#pragma unroll
        for (int bb = 0; bb < 4; ++bb) {
            int c = c0 + tx * 4 + bb;
            size_t o = (size_t)n * 256 + c;
            float v = acc[a][bb];
            emb[o] = v;
            unsigned short h = f2bf(v);
            eh[o] = h;
            el[o] = f2bf(v - bf2f(h));
        }
    }
}

// ---------------------------------------------------------------- K0d:
// se[n] = sum(emb^2) per code row, fp64 accumulate.
__global__ __launch_bounds__(256) void k0d_se(const float* __restrict__ emb,
                                              float* __restrict__ se) {
    const int w = threadIdx.x >> 6, lane = threadIdx.x & 63;
    const int n = blockIdx.x * 4 + w;
    const float4 v = *(const float4*)(emb + (size_t)n * 256 + lane * 4);
    double s = (double)v.x * v.x + (double)v.y * v.y + (double)v.z * v.z +
               (double)v.w * v.w;
#pragma unroll
    for (int m = 1; m < 64; m <<= 1) s += __shfl_xor(s, m);
    if (lane == 0) se[n] = (float)s;
}

// ---------------------------------------------------------------- K1:
// Fused bf16x2 (3-term) MFMA GEMM + argmin, A register-resident.
// Grid (NTOK/128, 8 slabs). Block 256 thr = 4 waves; wave w owns token rows
// [tokBase+w*32, +32) (A frags: 2mt x 8ks x hi/lo = 128 VGPRs, loaded once).
// B streamed in 32-code chunks, double-buffered 2x32KB LDS.
// LDS unit layout: [fmt][col][kg^col] (XOR swizzle) -> staging insts read two
// contiguous 512B row slices; ds_read_b128 is 2-way bank aliased (free).
__global__ __launch_bounds__(256, 2) void k1_dist_argmin(
    const unsigned short* __restrict__ zh, const unsigned short* __restrict__ zl,
    const unsigned short* __restrict__ eh, const unsigned short* __restrict__ el,
    const float* __restrict__ sz, const float* __restrict__ se,
    float* __restrict__ pval, int* __restrict__ pidx) {
    __shared__ short8 smem[2][2048];   // 2 x 32 KB
    const int tid = threadIdx.x;
    const int w = tid >> 6, lane = tid & 63;
    const int quad = lane >> 4, lr = lane & 15;
    const int tokBase = blockIdx.x * 128;
    const int rowBase = tokBase + w * 32;
    const int slab = blockIdx.y;
    const int slabBase = slab * 2048;

    // ---- A fragments: resident in registers for the whole kernel.
    short8 Ah[2][8], Al[2][8];
#pragma unroll
    for (int mt = 0; mt < 2; ++mt)
#pragma unroll
        for (int ks = 0; ks < 8; ++ks) {
            size_t o = (size_t)(rowBase + mt * 16 + lr) * 256 + ks * 32 + quad * 8;
            Ah[mt][ks] = *(const short8*)(zh + o);
            Al[mt][ks] = *(const short8*)(zl + o);
        }

    float szr[2][4];
#pragma unroll
    for (int mt = 0; mt < 2; ++mt)
#pragma unroll
        for (int rr = 0; rr < 4; ++rr)
            szr[mt][rr] = sz[rowBase + mt * 16 + quad * 4 + rr];

    float minv[2][4];
    int mini[2][4];
#pragma unroll
    for (int mt = 0; mt < 2; ++mt)
#pragma unroll
        for (int rr = 0; rr < 4; ++rr) {
            minv[mt][rr] = INFINITY;
            mini[mt][rr] = 0;
        }

    // stage chunk `ch` (32 codes x 256 k, hi+lo) into buffer `buf`
    auto stage = [&](int buf, int ch) {
        const int colBase = slabBase + ch * 32;
#pragma unroll
        for (int i = 0; i < 8; ++i) {
            int u = i * 256 + tid;      // 0..2047
            int fmt = u >> 10;          // wave-uniform (64-unit blocks)
            int u1 = u & 1023;
            int col = u1 >> 5, kgs = u1 & 31;
            int kg = kgs ^ col;         // XOR swizzle
            const unsigned short* g =
                (fmt ? el : eh) + (size_t)(colBase + col) * 256 + kg * 8;
            gload_lds16(g, (char*)&smem[buf][0] + (((size_t)i * 256 + w * 64) << 4));
        }
    };

    stage(0, 0);
    __syncthreads();

    for (int ch = 0; ch < 64; ++ch) {
        const int cur = ch & 1;
        if (ch + 1 < 64) stage(cur ^ 1, ch + 1);  // async prefetch

        f32x4v acc[2][2];
#pragma unroll
        for (int mt = 0; mt < 2; ++mt)
#pragma unroll
            for (int nt = 0; nt < 2; ++nt)
                acc[mt][nt] = (f32x4v){0.f, 0.f, 0.f, 0.f};

#pragma unroll
        for (int ks = 0; ks < 8; ++ks) {
            short8 Bh[2], Bl[2];
#pragma unroll
            for (int nt = 0; nt < 2; ++nt) {
                int col = nt * 16 + lr;
                int kgs = (ks * 4 + quad) ^ col;
                Bh[nt] = smem[cur][col * 32 + kgs];
                Bl[nt] = smem[cur][1024 + col * 32 + kgs];
            }
#pragma unroll
            for (int mt = 0; mt < 2; ++mt)
#pragma unroll
                for (int nt = 0; nt < 2; ++nt) {
                    f32x4v a = acc[mt][nt];
                    a = __builtin_amdgcn_mfma_f32_16x16x32_bf16(Ah[mt][ks], Bh[nt], a, 0, 0, 0);
                    a = __builtin_amdgcn_mfma_f32_16x16x32_bf16(Ah[mt][ks], Bl[nt], a, 0, 0, 0);
                    a = __builtin_amdgcn_mfma_f32_16x16x32_bf16(Al[mt][ks], Bh[nt], a, 0, 0, 0);
                    acc[mt][nt] = a;
                }
        }

        // fold: d = fl(fl(sz+se) - 2*dot); strict < keeps lowest index
        const int colBase = slabBase + ch * 32;
#pragma unroll
        for (int nt = 0; nt < 2; ++nt) {
            const int colg = colBase + nt * 16 + lr;
            const float sec = se[colg];
#pragma unroll
            for (int mt = 0; mt < 2; ++mt)
#pragma unroll
                for (int rr = 0; rr < 4; ++rr) {
                    float d = __fsub_rn(__fadd_rn(szr[mt][rr], sec),
                                        2.0f * acc[mt][nt][rr]);
                    if (d < minv[mt][rr]) {
                        minv[mt][rr] = d;
                        mini[mt][rr] = colg;
                    }
                }
        }
        __syncthreads();   // prefetch landed (vmcnt drain) + cur consumed
    }

    // reduce across the 16 lanes (lr) that share each output row
#pragma unroll
    for (int st = 1; st < 16; st <<= 1) {
#pragma unroll
        for (int mt = 0; mt < 2; ++mt)
#pragma unroll
            for (int rr = 0; rr < 4; ++rr) {
                float ov = __shfl_xor(minv[mt][rr], st);
                int oi = __shfl_xor(mini[mt][rr], st);
                if (ov < minv[mt][rr] ||
                    (ov == minv[mt][rr] && oi < mini[mt][rr])) {
                    minv[mt][rr] = ov;
                    mini[mt][rr] = oi;
                }
            }
    }
    if (lr == 0) {
#pragma unroll
        for (int mt = 0; mt < 2; ++mt)
#pragma unroll
            for (int rr = 0; rr < 4; ++rr) {
                int row = rowBase + mt * 16 + quad * 4 + rr;
                pval[(size_t)row * 8 + slab] = minv[mt][rr];
                pidx[(size_t)row * 8 + slab] = mini[mt][rr];
            }
    }
}

// ---------------------------------------------------------------- K3a:
// per-token: reduce 8 slab partials -> final index; rotation scalars
// alpha/beta; per-block loss partial (NO same-address atomics).
__global__ __launch_bounds__(256) void k3a_token(
    const float* __restrict__ z_flat, const float* __restrict__ emb,
    const float* __restrict__ pval, const int* __restrict__ pidx,
    float* __restrict__ alpha, float* __restrict__ beta,
    int* __restrict__ idxf, float* __restrict__ out,
    float* __restrict__ lpart) {
    __shared__ float red[4];
    const int w = threadIdx.x >> 6, lane = threadIdx.x & 63;
    const int t = blockIdx.x * 4 + w;
    int best = 0;
    if (lane == 0) {
        float bv = INFINITY;
        int bi = 0;
#pragma unroll
        for (int s = 0; s < 8; ++s) {
            float v = pval[(size_t)t * 8 + s];
            int ii = pidx[(size_t)t * 8 + s];
            if (v < bv || (v == bv && ii < bi)) { bv = v; bi = ii; }
        }
        best = bi;
    }
    best = __shfl(best, 0);

    const float4 zv = *(const float4*)(z_flat + (size_t)t * 256 + lane * 4);
    const float4 ev = *(const float4*)(emb + (size_t)best * 256 + lane * 4);
    float szs = zv.x * zv.x + zv.y * zv.y + zv.z * zv.z + zv.w * zv.w;
    float ses = ev.x * ev.x + ev.y * ev.y + ev.z * ev.z + ev.w * ev.w;
    float zes = zv.x * ev.x + zv.y * ev.y + zv.z * ev.z + zv.w * ev.w;
    float dx = zv.x - ev.x, dy = zv.y - ev.y, dz = zv.z - ev.z, dw = zv.w - ev.w;
    float sqs = dx * dx + dy * dy + dz * dz + dw * dw;
#pragma unroll
    for (int m = 1; m < 64; m <<= 1) {
        szs += __shfl_xor(szs, m);
        ses += __shfl_xor(ses, m);
        zes += __shfl_xor(zes, m);
        sqs += __shfl_xor(sqs, m);
    }
    if (lane == 0) {
        float ns = sqrtf(szs), nt = sqrtf(ses);
        float inv_s = 1.0f / (ns + EPSV);
        float inv_t = 1.0f / (nt + EPSV);
        float s2 = szs * inv_s;                      // z . u
        float su = szs * inv_s * inv_s;
        float sq = ses * inv_t * inv_t;
        float uq = zes * inv_s * inv_t;
        float nw = sqrtf(su + sq + 2.0f * uq);
        float inv_w = 1.0f / (nw + EPSV);
        float s1 = (s2 + zes * inv_t) * inv_w;       // z . w_
        float scale = nt * inv_s;
        float a = scale * (1.0f - 2.0f * s1 * inv_w * inv_s);
        float bb = scale * inv_t * 2.0f * (s2 - s1 * inv_w);
        alpha[t] = a;
        beta[t] = bb;
        idxf[t] = best;
        out[2097153 + t] = (float)best;
        red[w] = sqs;
    }
    __syncthreads();
    if (threadIdx.x == 0)
        lpart[blockIdx.x] = red[0] + red[1] + red[2] + red[3];
}

// ---------------------------------------------------------------- K4: loss
__global__ __launch_bounds__(256) void k4_loss(float* __restrict__ out,
                                               const float* __restrict__ lpart) {
    __shared__ float red[4];
    const int tid = threadIdx.x;
    float s = 0.0f;
    for (int i = tid; i < 2048; i += 256) s += lpart[i];
#pragma unroll
    for (int m = 1; m < 64; m <<= 1) s += __shfl_xor(s, m);
    if ((tid & 63) == 0) red[tid >> 6] = s;
    __syncthreads();
    if (tid == 0)
        out[2097152] = 1.25f * (red[0] + red[1] + red[2] + red[3]) *
                       (1.0f / 2097152.0f);
}

// ---------------------------------------------------------------- K3b:
// z_q[b][c][yx] = alpha[t]*z[b][c][yx] + beta[t]*emb[idx[t]][c]
__global__ __launch_bounds__(256) void k3b_zq(
    const float* __restrict__ zin, const float* __restrict__ emb,
    const float* __restrict__ alpha, const float* __restrict__ beta,
    const int* __restrict__ idxf, float* __restrict__ out) {
    const int i = blockIdx.x * 256 + threadIdx.x;
    const int c = (i >> 10) & 255;
    const int t = ((i >> 18) << 10) | (i & 1023);
    out[i] = alpha[t] * zin[i] + beta[t] * emb[(size_t)idxf[t] * 256 + c];
}

// ----------------------------------------------------------------
extern "C" void kernel_launch(void* const* d_in, const int* in_sizes, int n_in,
                              void* d_out, int out_size, void* d_ws,
                              size_t ws_size, hipStream_t stream) {
    (void)in_sizes; (void)n_in; (void)out_size; (void)ws_size;
    const float* zin = (const float*)d_in[0];
    const float* cb  = (const float*)d_in[1];
    const float* Wm  = (const float*)d_in[2];
    float* out = (float*)d_out;
    char* ws = (char*)d_ws;

    float*          z_flat = (float*)(ws + 0);                     //  8 MB
    unsigned short* zh     = (unsigned short*)(ws + 8388608);      //  4 MB
    unsigned short* zl     = (unsigned short*)(ws + 12582912);     //  4 MB
    float*          emb    = (float*)(ws + 16777216);              // 16 MB
    unsigned short* eh     = (unsigned short*)(ws + 33554432);     //  8 MB
    unsigned short* el     = (unsigned short*)(ws + 41943040);     //  8 MB
    float*          sz     = (float*)(ws + 50331648);              // 32 KB
    float*          se     = (float*)(ws + 50364416);              // 64 KB
    float*          pval   = (float*)(ws + 50429952);              // 256 KB
    int*            pidx   = (int*)(ws + 50692096);                // 256 KB
    float*          alpha  = (float*)(ws + 50954240);              // 32 KB
    float*          beta   = (float*)(ws + 50987008);              // 32 KB
    int*            idxf   = (int*)(ws + 51019776);                // 32 KB
    float*          lpart  = (float*)(ws + 51052544);              //  8 KB

    k0a_transpose<<<dim3(16, 4, 8), 256, 0, stream>>>(zin, z_flat, zh, zl);
    k0b_sz<<<2048, 256, 0, stream>>>(z_flat, sz);
    k0c_emb<<<dim3(256, 4), 256, 0, stream>>>(cb, Wm, emb, eh, el);
    k0d_se<<<4096, 256, 0, stream>>>(emb, se);
    k1_dist_argmin<<<dim3(64, 8), 256, 0, stream>>>(zh, zl, eh, el, sz, se,
                                                    pval, pidx);
    k3a_token<<<2048, 256, 0, stream>>>(z_flat, emb, pval, pidx, alpha, beta,
                                        idxf, out, lpart);
    k4_loss<<<1, 256, 0, stream>>>(out, lpart);
    k3b_zq<<<8192, 256, 0, stream>>>(zin, emb, alpha, beta, idxf, out);
}